// Round 11
// baseline (328.196 us; speedup 1.0000x reference)
//
#include <hip/hip_runtime.h>
#include <hip/hip_bf16.h>

#define N_NODES 32768
#define N_EDGES 196608
#define N_GRAPHS 256
#define DEG 6
#define HID 128
#define RVD 16
#define EMB 112
#define VOCAB 128
#define TGT 256
#define DEPTH 5

#define LOG7 1.9459101090932196f
#define ILOG7 0.5138983423697507f

typedef __hip_bfloat16 bf16;
using frag_ab = __attribute__((ext_vector_type(8))) short;   // 8 bf16
using frag_cd = __attribute__((ext_vector_type(4))) float;   // 4 f32
typedef float f32x2 __attribute__((ext_vector_type(2)));

static __device__ __forceinline__ float b2f(bf16 x) { return __bfloat162float(x); }
static __device__ __forceinline__ bf16  f2b(float x) { return __float2bfloat16(x); }
static __device__ __forceinline__ float us2f(unsigned short u) {
    unsigned int x = ((unsigned int)u) << 16;
    return __uint_as_float(x);
}
static __device__ __forceinline__ unsigned short f2us(float x) {
    bf16 b = __float2bfloat16(x);
    return *reinterpret_cast<unsigned short*>(&b);
}

// ---------------- unified prep: encode + packs + bond table, one dispatch ----------------
#define PB_ENC  16384
#define PB_WB   (PB_ENC + 640)
#define PB_WC   (PB_WB + 1600)
#define PB_WR   (PB_WC + 80)
#define PB_CODE (PB_WR + 768)
#define PB_T    (PB_CODE + 320)

__global__ __launch_bounds__(256) void prep_k(const int* __restrict__ af, const float* __restrict__ rx,
                                              const float* __restrict__ aemb, bf16* __restrict__ h,
                                              const float* __restrict__ preW, const float* __restrict__ preB,
                                              const float* __restrict__ postW,
                                              const int* __restrict__ bfeat, const float* __restrict__ bemb,
                                              bf16* __restrict__ wb, bf16* __restrict__ wc,
                                              bf16* __restrict__ wrB, unsigned char* __restrict__ codeA,
                                              bf16* __restrict__ Tb) {
    int blk = blockIdx.x, tid = threadIdx.x;
    if (blk < PB_ENC) {
        int v = blk * 2 + (tid >> 7), c = tid & 127;
        float val;
        if (c < EMB) {
            val = 0.f;
            #pragma unroll
            for (int i = 0; i < 9; ++i) {
                int f = af[v * 9 + i];
                val += aemb[(i * VOCAB + f) * EMB + c];
            }
        } else {
            val = rx[v * RVD + (c - EMB)];
        }
        h[(size_t)v * HID + c] = f2b(val);
    } else if (blk < PB_WB) {
        int idx = (blk - PB_ENC) * 256 + tid;
        if (idx < DEPTH * 32768) {
            int j = idx & 7, L = (idx >> 3) & 63, nt = (idx >> 9) & 15, ks = (idx >> 13) & 3, l = idx >> 15;
            int k = ks * 32 + ((L >> 4) * 8) + j;
            int n = nt * 16 + (L & 15);
            const float* W = preW + (size_t)l * 384 * 128;
            float v = (n < 128) ? W[k * 128 + n] : W[(128 + k) * 128 + (n - 128)];
            wb[idx] = f2b(v);
        }
    } else if (blk < PB_WC) {
        int idx = (blk - PB_WB) * 256 + tid;
        if (idx < DEPTH * 81920) {
            int j = idx & 7, L = (idx >> 3) & 63, nt = (idx >> 9) & 7;
            int t = idx >> 12;
            int ks = t % 20, l = t / 20;
            int k = ks * 32 + ((L >> 4) * 8) + j;
            int n = nt * 16 + (L & 15);
            const float* W = postW + (size_t)l * 1664 * 128;
            float v;
            if (k < 128) {
                v = W[k * 128 + n];
            } else {
                int jj = k - 128;
                v = W[(128 + jj) * 128 + n] + LOG7 * W[(640 + jj) * 128 + n] + ILOG7 * W[(1152 + jj) * 128 + n];
            }
            wc[idx] = f2b(v);
        }
    } else if (blk < PB_WR) {
        int idx = (blk - PB_WC) * 256 + tid;
        if (idx < DEPTH * 4096) {
            int j = idx & 7, L = (idx >> 3) & 63, nt = (idx >> 9) & 7, l = idx >> 12;
            int k = ((L >> 4) * 8) + j;
            int n = nt * 16 + (L & 15);
            float v = (k < 16) ? preW[(size_t)l * 384 * 128 + (368 + k) * 128 + n] : 0.f;
            wrB[idx] = f2b(v);
        }
    } else if (blk < PB_CODE) {
        int e = (blk - PB_WR) * 256 + tid;
        if (e < N_EDGES)
            codeA[e] = (unsigned char)(bfeat[e * 3] | (bfeat[e * 3 + 1] << 2) | (bfeat[e * 3 + 2] << 4));
    } else {
        if (tid < 128) {
            int t = blk - PB_CODE;
            int l = t >> 6, cd = t & 63, c = tid;
            int f0 = cd & 3, f1 = (cd >> 2) & 3, f2 = cd >> 4;
            const float* W = preW + (size_t)l * 384 * 128 + 256 * 128;
            float acc = preB[l * 128 + c];
            #pragma unroll 4
            for (int k = 0; k < EMB; ++k) {
                float bsk = bemb[(0 * VOCAB + f0) * EMB + k]
                          + bemb[(1 * VOCAB + f1) * EMB + k]
                          + bemb[(2 * VOCAB + f2) * EMB + k];
                acc += bsk * W[k * 128 + c];
            }
            Tb[(size_t)(l * 64 + cd) * 128 + c] = f2b(acc);
        }
    }
}

// ---------------- layer-0 Z12 GEMM v2: B-reuse tiling + vectorized stores ----------------
// 64-row tile, 256 threads / 4 waves = (mh 0..1) x (ng 0..1); each wave 32 rows x 128 cols.
// B-frags reused across 2 m-tiles -> block B-traffic halved (256->128 KB).
// Stores staged through LDS ztile -> dwordx4 (was 64 scalar 2B stores/thread).
__global__ __launch_bounds__(256, 4) void gemm_z12(const bf16* __restrict__ A,
                                                   const bf16* __restrict__ Bp,
                                                   bf16* __restrict__ C) {
    __shared__ __align__(16) bf16 ztile[64 * 264];   // 33,792 B -> 4 blocks/CU
    int lane = threadIdx.x & 63;
    int wave = threadIdx.x >> 6;
    int ml = lane & 15, quad = lane >> 4;
    int mh = wave >> 1, ng = wave & 1;
    int row0 = blockIdx.x * 64;

    frag_cd acc[2][8];
    #pragma unroll
    for (int m2 = 0; m2 < 2; ++m2)
        #pragma unroll
        for (int nt = 0; nt < 8; ++nt)
            #pragma unroll
            for (int i = 0; i < 4; ++i) acc[m2][nt][i] = 0.f;

    const frag_ab* Bf = (const frag_ab*)Bp;
    #pragma unroll
    for (int ks = 0; ks < 4; ++ks) {
        #pragma unroll
        for (int nh = 0; nh < 2; ++nh) {
            frag_ab bb[4];
            #pragma unroll
            for (int nt = 0; nt < 4; ++nt)
                bb[nt] = Bf[(ks * 16 + ng * 8 + nh * 4 + nt) * 64 + lane];
            #pragma unroll
            for (int m2 = 0; m2 < 2; ++m2) {
                frag_ab a = *(const frag_ab*)(A + (size_t)(row0 + mh * 32 + m2 * 16 + ml) * 128
                                              + ks * 32 + quad * 8);
                #pragma unroll
                for (int nt = 0; nt < 4; ++nt)
                    acc[m2][nh * 4 + nt] =
                        __builtin_amdgcn_mfma_f32_16x16x32_bf16(a, bb[nt], acc[m2][nh * 4 + nt], 0, 0, 0);
            }
        }
    }
    #pragma unroll
    for (int m2 = 0; m2 < 2; ++m2)
        #pragma unroll
        for (int nt = 0; nt < 8; ++nt) {
            int col = ng * 128 + nt * 16 + ml;
            #pragma unroll
            for (int r = 0; r < 4; ++r) {
                int lr = mh * 32 + m2 * 16 + quad * 4 + r;
                ztile[lr * 264 + col] = f2b(acc[m2][nt][r]);
            }
        }
    __syncthreads();
    int t = threadIdx.x;
    int row = t >> 2, cq = t & 3;   // 64 ch per thread
    unsigned short* dst = (unsigned short*)C + (size_t)(row0 + row) * 256 + cq * 64;
    const unsigned short* srcp = (const unsigned short*)ztile + row * 264 + cq * 64;
    #pragma unroll
    for (int k2 = 0; k2 < 8; ++k2)
        *(frag_ab*)(dst + k2 * 8) = *(const frag_ab*)(srcp + k2 * 8);
}

// ---------------- fully fused layer (R7/v6 config: best measured) ----------------
// Block = 32 nodes, 256 threads / 4 waves, LDS 39.4 KB -> 4 blocks/CU.
// agg phase: per-wave 2-slot gather pipeline, in-lane rdot via relds broadcast + wr2 regs.
// GEMM phase: wave = ng covers all 32 rows; vectorized LDS-staged epilogue.
__global__ __launch_bounds__(256, 4) void fused_layer(bf16* __restrict__ h,
                                                      const bf16* __restrict__ Zcur,
                                                      const int* __restrict__ src,
                                                      const unsigned char* __restrict__ code,
                                                      const float* __restrict__ rand_edge,
                                                      const bf16* __restrict__ Tb,
                                                      const float* __restrict__ Wr,
                                                      const bf16* __restrict__ Bp,
                                                      const float* __restrict__ bias,
                                                      const bf16* __restrict__ Bn,
                                                      bf16* __restrict__ Znext) {
    __shared__ __align__(16) bf16 agg_lds[32 * 520];   // 33,280 B
    __shared__ __align__(16) float relds[4][384];      // 6,144 B

    int tid = threadIdx.x;
    int lane = tid & 63, wave = tid >> 6;
    int ml = lane & 15, quad = lane >> 4;
    int row0 = blockIdx.x * 32;

    const unsigned short* Zu = (const unsigned short*)Zcur;
    const unsigned short* Tu = (const unsigned short*)Tb;
    unsigned short* Ag = (unsigned short*)agg_lds;
    int c = lane * 2;

    // ================= agg phase: per-wave, no barriers (2-slot pipeline) =================
    {
        const int vbase = row0 + wave * 8;

        f32x2 wr2[16];
        #pragma unroll
        for (int k = 0; k < 16; ++k) {
            float2 w2 = *(const float2*)(Wr + k * 128 + c);
            wr2[k].x = w2.x; wr2[k].y = w2.y;
        }

        {
            const float2* rb = (const float2*)(rand_edge + (size_t)vbase * 96);
            float2 a0 = rb[lane], a1 = rb[lane + 64], a2 = rb[lane + 128];
            float2* rl = (float2*)relds[wave];
            rl[lane] = a0; rl[lane + 64] = a1; rl[lane + 128] = a2;
        }
        float2 rh0, rh1, rh2;

        int svs[2][6]; int cds[2][6];
        ushort2 z1u[2][6], tvu[2][6], z2u[2];

        {
            const int2* sp = (const int2*)(src + vbase * 6);
            int2 a = sp[0], b = sp[1], d = sp[2];
            svs[0][0] = a.x; svs[0][1] = a.y; svs[0][2] = b.x;
            svs[0][3] = b.y; svs[0][4] = d.x; svs[0][5] = d.y;
            const unsigned short* cp = (const unsigned short*)(code + vbase * 6);
            unsigned short x = cp[0], y = cp[1], z = cp[2];
            cds[0][0] = x & 255; cds[0][1] = x >> 8; cds[0][2] = y & 255;
            cds[0][3] = y >> 8;  cds[0][4] = z & 255; cds[0][5] = z >> 8;
        }
        z2u[0] = *(const ushort2*)(Zu + (size_t)vbase * 256 + 128 + c);
        #pragma unroll
        for (int j = 0; j < 6; ++j) z1u[0][j] = *(const ushort2*)(Zu + (size_t)svs[0][j] * 256 + c);
        #pragma unroll
        for (int j = 0; j < 6; ++j) tvu[0][j] = *(const ushort2*)(Tu + cds[0][j] * 128 + c);
        {
            const int2* sp = (const int2*)(src + (vbase + 1) * 6);
            int2 a = sp[0], b = sp[1], d = sp[2];
            svs[1][0] = a.x; svs[1][1] = a.y; svs[1][2] = b.x;
            svs[1][3] = b.y; svs[1][4] = d.x; svs[1][5] = d.y;
            const unsigned short* cp = (const unsigned short*)(code + (vbase + 1) * 6);
            unsigned short x = cp[0], y = cp[1], z = cp[2];
            cds[1][0] = x & 255; cds[1][1] = x >> 8; cds[1][2] = y & 255;
            cds[1][3] = y >> 8;  cds[1][4] = z & 255; cds[1][5] = z >> 8;
        }

        #pragma unroll
        for (int i = 0; i < 8; ++i) {
            const int s = i & 1, t = s ^ 1;
            if (i == 2) {
                const float2* rb2 = (const float2*)(rand_edge + (size_t)(vbase + 4) * 96);
                rh0 = rb2[lane]; rh1 = rb2[lane + 64]; rh2 = rb2[lane + 128];
            }
            if (i == 4) {
                float2* rl = (float2*)relds[wave];
                rl[lane] = rh0; rl[lane + 64] = rh1; rl[lane + 128] = rh2;
            }
            if (i < 7) {
                z2u[t] = *(const ushort2*)(Zu + (size_t)(vbase + i + 1) * 256 + 128 + c);
                #pragma unroll
                for (int j = 0; j < 6; ++j) z1u[t][j] = *(const ushort2*)(Zu + (size_t)svs[t][j] * 256 + c);
                #pragma unroll
                for (int j = 0; j < 6; ++j) tvu[t][j] = *(const ushort2*)(Tu + cds[t][j] * 128 + c);
            }
            if (i < 6) {
                const int2* sp = (const int2*)(src + (vbase + i + 2) * 6);
                int2 a = sp[0], b = sp[1], d = sp[2];
                svs[s][0] = a.x; svs[s][1] = a.y; svs[s][2] = b.x;
                svs[s][3] = b.y; svs[s][4] = d.x; svs[s][5] = d.y;
                const unsigned short* cp = (const unsigned short*)(code + (vbase + i + 2) * 6);
                unsigned short x = cp[0], y = cp[1], z = cp[2];
                cds[s][0] = x & 255; cds[s][1] = x >> 8; cds[s][2] = y & 255;
                cds[s][3] = y >> 8;  cds[s][4] = z & 255; cds[s][5] = z >> 8;
            }

            float z2a = us2f(z2u[s].x), z2b = us2f(z2u[s].y);
            f32x2 s2  = {0.f, 0.f}, ss2 = {0.f, 0.f};
            f32x2 mx2 = {-1e30f, -1e30f}, mn2 = {1e30f, 1e30f};
            #pragma unroll
            for (int j = 0; j < 6; ++j) {
                const float4* rp = (const float4*)&relds[wave][(i & 3) * 96 + j * 16];
                float4 r0 = rp[0], r1 = rp[1], r2 = rp[2], r3 = rp[3];
                f32x2 v2;
                v2.x = us2f(z1u[s][j].x) + z2a + us2f(tvu[s][j].x);
                v2.y = us2f(z1u[s][j].y) + z2b + us2f(tvu[s][j].y);
                float rk[16] = {r0.x, r0.y, r0.z, r0.w, r1.x, r1.y, r1.z, r1.w,
                                r2.x, r2.y, r2.z, r2.w, r3.x, r3.y, r3.z, r3.w};
                #pragma unroll
                for (int k = 0; k < 16; ++k) v2 += rk[k] * wr2[k];
                v2 = __builtin_elementwise_max(v2, (f32x2){0.f, 0.f});
                s2 += v2;
                ss2 += v2 * v2;
                mx2 = __builtin_elementwise_max(mx2, v2);
                mn2 = __builtin_elementwise_min(mn2, v2);
            }
            f32x2 mean2 = s2 * (1.f / 6.f);
            f32x2 msq2  = ss2 * (1.f / 6.f);
            f32x2 var2  = __builtin_elementwise_max(msq2 - mean2 * mean2, (f32x2){0.f, 0.f});
            float sda = sqrtf(var2.x + 1e-5f), sdb = sqrtf(var2.y + 1e-5f);
            int lrow = wave * 8 + i;
            size_t base = (size_t)lrow * 520 + c;
            *(ushort2*)(Ag + base)       = make_ushort2(f2us(mean2.x), f2us(mean2.y));
            *(ushort2*)(Ag + base + 128) = make_ushort2(f2us(mx2.x),   f2us(mx2.y));
            *(ushort2*)(Ag + base + 256) = make_ushort2(f2us(mn2.x),   f2us(mn2.y));
            *(ushort2*)(Ag + base + 384) = make_ushort2(f2us(sda),     f2us(sdb));
        }
    }
    __syncthreads();   // (1) agg tile complete

    // ================= GEMM phase =================
    int ng = wave;

    frag_cd acc[2][2];
    #pragma unroll
    for (int m2 = 0; m2 < 2; ++m2)
        #pragma unroll
        for (int nt = 0; nt < 2; ++nt)
            #pragma unroll
            for (int i = 0; i < 4; ++i) acc[m2][nt][i] = 0.f;

    const frag_ab* Bf = (const frag_ab*)Bp;
    #pragma unroll
    for (int ks = 0; ks < 4; ++ks) {
        frag_ab b0 = Bf[(ks * 8 + ng * 2 + 0) * 64 + lane];
        frag_ab b1 = Bf[(ks * 8 + ng * 2 + 1) * 64 + lane];
        #pragma unroll
        for (int m2 = 0; m2 < 2; ++m2) {
            frag_ab a = *(const frag_ab*)(h + (size_t)(row0 + m2 * 16 + ml) * 128 + ks * 32 + quad * 8);
            acc[m2][0] = __builtin_amdgcn_mfma_f32_16x16x32_bf16(a, b0, acc[m2][0], 0, 0, 0);
            acc[m2][1] = __builtin_amdgcn_mfma_f32_16x16x32_bf16(a, b1, acc[m2][1], 0, 0, 0);
        }
    }
    #pragma unroll
    for (int ks = 0; ks < 16; ++ks) {
        frag_ab b0 = Bf[((4 + ks) * 8 + ng * 2 + 0) * 64 + lane];
        frag_ab b1 = Bf[((4 + ks) * 8 + ng * 2 + 1) * 64 + lane];
        #pragma unroll
        for (int m2 = 0; m2 < 2; ++m2) {
            frag_ab a = *(const frag_ab*)(agg_lds + (size_t)(m2 * 16 + ml) * 520 + ks * 32 + quad * 8);
            acc[m2][0] = __builtin_amdgcn_mfma_f32_16x16x32_bf16(a, b0, acc[m2][0], 0, 0, 0);
            acc[m2][1] = __builtin_amdgcn_mfma_f32_16x16x32_bf16(a, b1, acc[m2][1], 0, 0, 0);
        }
    }

    __syncthreads();   // (2)

    float* pgemm = (float*)agg_lds;   // [32][132]
    #pragma unroll
    for (int nt = 0; nt < 2; ++nt) {
        int col = (ng * 2 + nt) * 16 + ml;
        float bs_ = bias[col];
        #pragma unroll
        for (int m2 = 0; m2 < 2; ++m2) {
            #pragma unroll
            for (int r2 = 0; r2 < 4; ++r2) {
                int lr = m2 * 16 + quad * 4 + r2;
                pgemm[lr * 132 + col] = acc[m2][nt][r2] + bs_;
            }
        }
    }
    __syncthreads();   // (3)

    bf16* newh = agg_lds + 8448;   // [32][136]
    {
        int row = tid >> 3, cg = tid & 7;
        const float4* pg = (const float4*)(pgemm + row * 132 + cg * 16);
        float4 p0 = pg[0], p1 = pg[1], p2 = pg[2], p3 = pg[3];
        unsigned short* hrow = (unsigned short*)(h + (size_t)(row0 + row) * 128 + cg * 16);
        frag_ab h0 = *(const frag_ab*)hrow;
        frag_ab h1 = *(const frag_ab*)(hrow + 8);
        float nv[16] = {p0.x, p0.y, p0.z, p0.w, p1.x, p1.y, p1.z, p1.w,
                        p2.x, p2.y, p2.z, p2.w, p3.x, p3.y, p3.z, p3.w};
        #pragma unroll
        for (int j = 0; j < 8; ++j) nv[j]     += us2f((unsigned short)h0[j]);
        #pragma unroll
        for (int j = 0; j < 8; ++j) nv[8 + j] += us2f((unsigned short)h1[j]);
        frag_ab o0, o1;
        #pragma unroll
        for (int j = 0; j < 8; ++j) o0[j] = (short)f2us(nv[j]);
        #pragma unroll
        for (int j = 0; j < 8; ++j) o1[j] = (short)f2us(nv[8 + j]);
        *(frag_ab*)hrow = o0;
        *(frag_ab*)(hrow + 8) = o1;
        *(frag_ab*)&newh[row * 136 + cg * 16] = o0;
        *(frag_ab*)&newh[row * 136 + cg * 16 + 8] = o1;
    }

    if (Bn) {
        __syncthreads();   // (4)
        const frag_ab* Bf2 = (const frag_ab*)Bn;
        frag_cd a2[2][4];
        #pragma unroll
        for (int m2 = 0; m2 < 2; ++m2)
            #pragma unroll
            for (int nt = 0; nt < 4; ++nt)
                #pragma unroll
                for (int i = 0; i < 4; ++i) a2[m2][nt][i] = 0.f;
        #pragma unroll
        for (int ks = 0; ks < 4; ++ks) {
            frag_ab bb[4];
            #pragma unroll
            for (int nt = 0; nt < 4; ++nt)
                bb[nt] = Bf2[(ks * 16 + ng * 4 + nt) * 64 + lane];
            #pragma unroll
            for (int m2 = 0; m2 < 2; ++m2) {
                frag_ab a = *(const frag_ab*)&newh[(m2 * 16 + ml) * 136 + ks * 32 + quad * 8];
                #pragma unroll
                for (int nt = 0; nt < 4; ++nt)
                    a2[m2][nt] = __builtin_amdgcn_mfma_f32_16x16x32_bf16(a, bb[nt], a2[m2][nt], 0, 0, 0);
            }
        }
        bf16* ztile = agg_lds;   // [32][264]
        #pragma unroll
        for (int m2 = 0; m2 < 2; ++m2) {
            #pragma unroll
            for (int nt = 0; nt < 4; ++nt) {
                int col = (ng * 4 + nt) * 16 + ml;
                #pragma unroll
                for (int r2 = 0; r2 < 4; ++r2) {
                    int lr = m2 * 16 + quad * 4 + r2;
                    ztile[lr * 264 + col] = f2b(a2[m2][nt][r2]);
                }
            }
        }
        __syncthreads();   // (5)
        int row = tid >> 3, cg = tid & 7;
        unsigned short* zr = (unsigned short*)(Znext + (size_t)(row0 + row) * 256 + cg * 32);
        const unsigned short* zs = (const unsigned short*)ztile + row * 264 + cg * 32;
        #pragma unroll
        for (int k2 = 0; k2 < 4; ++k2)
            *(frag_ab*)(zr + k2 * 8) = *(const frag_ab*)(zs + k2 * 8);
    }
}

// ---------------- readout v2: 256 threads, vectorized reduce + split-K matvecs (all f32 math) ----------------
__global__ __launch_bounds__(256) void readout(const bf16* __restrict__ h, const float* __restrict__ W1,
                                               const float* __restrict__ b1, const float* __restrict__ W2,
                                               const float* __restrict__ b2, float* __restrict__ out) {
    __shared__ float ssum[16][16][8];   // [vs][cg][8ch] 8 KB
    __shared__ float smax[16][16][8];   // 8 KB
    __shared__ float r[384];
    __shared__ float part[2][128];
    __shared__ float y1[128];
    int g = blockIdx.x, t = threadIdx.x;
    int cg = t & 15, vs = t >> 4;

    // phase 1: each thread reduces 8 nodes x 8 channels (short8 loads)
    float fs[8], fm[8];
    #pragma unroll
    for (int j = 0; j < 8; ++j) { fs[j] = 0.f; fm[j] = -1e30f; }
    const unsigned short* hb = (const unsigned short*)h + ((size_t)g * 128 + vs * 8) * 128 + cg * 8;
    #pragma unroll
    for (int k = 0; k < 8; ++k) {
        frag_ab v = *(const frag_ab*)(hb + (size_t)k * 128);
        #pragma unroll
        for (int j = 0; j < 8; ++j) {
            float x = us2f((unsigned short)v[j]);
            fs[j] += x; fm[j] = fmaxf(fm[j], x);
        }
    }
    #pragma unroll
    for (int j = 0; j < 8; ++j) { ssum[vs][cg][j] = fs[j]; smax[vs][cg][j] = fm[j]; }
    __syncthreads();
    #pragma unroll
    for (int st = 8; st >= 1; st >>= 1) {
        if (vs < st) {
            #pragma unroll
            for (int j = 0; j < 8; ++j) {
                ssum[vs][cg][j] += ssum[vs + st][cg][j];
                smax[vs][cg][j] = fmaxf(smax[vs][cg][j], smax[vs + st][cg][j]);
            }
        }
        __syncthreads();
    }
    if (vs == 0) {
        #pragma unroll
        for (int j = 0; j < 8; ++j) {
            int c = cg * 8 + j;
            float s = ssum[0][cg][j];
            r[c] = s * (1.f / 128.f);
            r[128 + c] = s;
            r[256 + c] = smax[0][cg][j];
        }
    }
    __syncthreads();

    // phase 2: y1 = relu(r @ W1 + b1), split-K by 2 (192 each)
    {
        int c = t & 127, half = t >> 7;
        float a1 = (half == 0) ? b1[c] : 0.f;
        int k0 = half * 192;
        for (int k = 0; k < 192; ++k)
            a1 += r[k0 + k] * W1[(size_t)(k0 + k) * 128 + c];
        part[half][c] = a1;
    }
    __syncthreads();
    if (t < 128) y1[t] = fmaxf(part[0][t] + part[1][t], 0.f);
    __syncthreads();

    // phase 3: out = y1 @ W2 + b2 (256 outputs, 1 per thread)
    {
        float a2 = b2[t];
        for (int k = 0; k < 128; ++k)
            a2 += y1[k] * W2[(size_t)k * 256 + t];
        out[(size_t)g * 256 + t] = a2;
    }
}

// ---------------- launch ----------------
extern "C" void kernel_launch(void* const* d_in, const int* in_sizes, int n_in,
                              void* d_out, int out_size, void* d_ws, size_t ws_size,
                              hipStream_t stream) {
    const int*   atom_feats = (const int*)d_in[0];
    const int*   bond_feats = (const int*)d_in[1];
    const int*   src        = (const int*)d_in[2];
    const float* rand_x     = (const float*)d_in[6];
    const float* rand_edge  = (const float*)d_in[7];
    const float* atom_emb   = (const float*)d_in[8];
    const float* bond_emb   = (const float*)d_in[9];
    const float* pre_W      = (const float*)d_in[10];
    const float* pre_b      = (const float*)d_in[11];
    const float* post_W     = (const float*)d_in[12];
    const float* post_b     = (const float*)d_in[13];
    const float* ro_W1      = (const float*)d_in[14];
    const float* ro_b1      = (const float*)d_in[15];
    const float* ro_W2      = (const float*)d_in[16];
    const float* ro_b2      = (const float*)d_in[17];

    char* p = (char*)d_ws;
    auto alloc = [&](size_t bytes) {
        char* r = p;
        p += (bytes + 255) & ~(size_t)255;
        return r;
    };
    bf16*  h    = (bf16*) alloc((size_t)N_NODES * HID * 2);      // 8 MB (bf16 state)
    bf16*  z12a = (bf16*) alloc((size_t)N_NODES * 256 * 2);      // 16 MB (ping)
    bf16*  z12b = (bf16*) alloc((size_t)N_NODES * 256 * 2);      // 16 MB (pong)
    bf16*  wb   = (bf16*) alloc((size_t)DEPTH * 32768 * 2);
    bf16*  wc   = (bf16*) alloc((size_t)DEPTH * 81920 * 2);
    bf16*  wrB  = (bf16*) alloc((size_t)DEPTH * 4096 * 2);       // 40 KB (legacy pack, unused)
    bf16*  Tb   = (bf16*) alloc((size_t)DEPTH * 64 * 128 * 2);   // 80 KB
    unsigned char* code = (unsigned char*)alloc(N_EDGES);        // 192 KB

    // unified prep (encode + all packs + bond table)
    prep_k<<<PB_T, 256, 0, stream>>>(atom_feats, rand_x, atom_emb, h,
                                     pre_W, pre_b, post_W,
                                     bond_feats, bond_emb,
                                     wb, wc, wrB, code, Tb);

    // layer-0 Z12
    gemm_z12<<<N_NODES / 64, 256, 0, stream>>>(h, wb, z12a);

    bf16* zc = z12a;
    bf16* zn = z12b;
    for (int l = 0; l < DEPTH; ++l) {
        const bf16* wbn = (l + 1 < DEPTH) ? (wb + (size_t)(l + 1) * 32768) : nullptr;
        fused_layer<<<N_NODES / 32, 256, 0, stream>>>(
            h, zc, src, code, rand_edge,
            Tb + (size_t)l * 8192,
            pre_W + (size_t)l * 384 * 128 + 368 * 128,   // Wr: rand-edge rows of pretrans W
            wc + (size_t)l * 81920,
            post_b + l * HID,
            wbn, zn);
        bf16* t = zc; zc = zn; zn = t;
    }

    readout<<<N_GRAPHS, 256, 0, stream>>>(h, ro_W1, ro_b1, ro_W2, ro_b2, (float*)d_out);
}

// Round 12
// 317.193 us; speedup vs baseline: 1.0347x; 1.0347x over previous
//
#include <hip/hip_runtime.h>
#include <hip/hip_bf16.h>

#define N_NODES 32768
#define N_EDGES 196608
#define N_GRAPHS 256
#define DEG 6
#define HID 128
#define RVD 16
#define EMB 112
#define VOCAB 128
#define TGT 256
#define DEPTH 5

#define LOG7 1.9459101090932196f
#define ILOG7 0.5138983423697507f

typedef __hip_bfloat16 bf16;
using frag_ab = __attribute__((ext_vector_type(8))) short;   // 8 bf16
using frag_cd = __attribute__((ext_vector_type(4))) float;   // 4 f32
typedef float f32x2 __attribute__((ext_vector_type(2)));

static __device__ __forceinline__ float b2f(bf16 x) { return __bfloat162float(x); }
static __device__ __forceinline__ bf16  f2b(float x) { return __float2bfloat16(x); }
static __device__ __forceinline__ float us2f(unsigned short u) {
    unsigned int x = ((unsigned int)u) << 16;
    return __uint_as_float(x);
}
static __device__ __forceinline__ unsigned short f2us(float x) {
    bf16 b = __float2bfloat16(x);
    return *reinterpret_cast<unsigned short*>(&b);
}

// ---------------- unified prep: encode (float4-vectorized) + packs + bond table ----------------
#define PB_ENC  4096
#define PB_WB   (PB_ENC + 640)
#define PB_WC   (PB_WB + 1600)
#define PB_WR   (PB_WC + 80)
#define PB_CODE (PB_WR + 768)
#define PB_T    (PB_CODE + 320)

__global__ __launch_bounds__(256) void prep_k(const int* __restrict__ af, const float* __restrict__ rx,
                                              const float* __restrict__ aemb, bf16* __restrict__ h,
                                              const float* __restrict__ preW, const float* __restrict__ preB,
                                              const float* __restrict__ postW,
                                              const int* __restrict__ bfeat, const float* __restrict__ bemb,
                                              bf16* __restrict__ wb, bf16* __restrict__ wc,
                                              bf16* __restrict__ wrB, unsigned char* __restrict__ codeA,
                                              bf16* __restrict__ Tb) {
    int blk = blockIdx.x, tid = threadIdx.x;
    if (blk < PB_ENC) {
        // 8 nodes/block, 32 threads/node, 4 channels/thread (float4 gathers, ushort4 store)
        int v = blk * 8 + (tid >> 5);
        int cg = (tid & 31) * 4;
        float4 val;
        if (cg < EMB) {
            val = make_float4(0.f, 0.f, 0.f, 0.f);
            #pragma unroll
            for (int i = 0; i < 9; ++i) {
                int f = af[v * 9 + i];
                float4 e = *(const float4*)(aemb + ((size_t)(i * VOCAB + f)) * EMB + cg);
                val.x += e.x; val.y += e.y; val.z += e.z; val.w += e.w;
            }
        } else {
            val = *(const float4*)(rx + (size_t)v * RVD + (cg - EMB));
        }
        ushort4 o;
        o.x = f2us(val.x); o.y = f2us(val.y); o.z = f2us(val.z); o.w = f2us(val.w);
        *(ushort4*)((unsigned short*)h + (size_t)v * HID + cg) = o;
    } else if (blk < PB_WB) {
        int idx = (blk - PB_ENC) * 256 + tid;
        if (idx < DEPTH * 32768) {
            int j = idx & 7, L = (idx >> 3) & 63, nt = (idx >> 9) & 15, ks = (idx >> 13) & 3, l = idx >> 15;
            int k = ks * 32 + ((L >> 4) * 8) + j;
            int n = nt * 16 + (L & 15);
            const float* W = preW + (size_t)l * 384 * 128;
            float v = (n < 128) ? W[k * 128 + n] : W[(128 + k) * 128 + (n - 128)];
            wb[idx] = f2b(v);
        }
    } else if (blk < PB_WC) {
        int idx = (blk - PB_WB) * 256 + tid;
        if (idx < DEPTH * 81920) {
            int j = idx & 7, L = (idx >> 3) & 63, nt = (idx >> 9) & 7;
            int t = idx >> 12;
            int ks = t % 20, l = t / 20;
            int k = ks * 32 + ((L >> 4) * 8) + j;
            int n = nt * 16 + (L & 15);
            const float* W = postW + (size_t)l * 1664 * 128;
            float v;
            if (k < 128) {
                v = W[k * 128 + n];
            } else {
                int jj = k - 128;
                v = W[(128 + jj) * 128 + n] + LOG7 * W[(640 + jj) * 128 + n] + ILOG7 * W[(1152 + jj) * 128 + n];
            }
            wc[idx] = f2b(v);
        }
    } else if (blk < PB_WR) {
        int idx = (blk - PB_WC) * 256 + tid;
        if (idx < DEPTH * 4096) {
            int j = idx & 7, L = (idx >> 3) & 63, nt = (idx >> 9) & 7, l = idx >> 12;
            int k = ((L >> 4) * 8) + j;
            int n = nt * 16 + (L & 15);
            float v = (k < 16) ? preW[(size_t)l * 384 * 128 + (368 + k) * 128 + n] : 0.f;
            wrB[idx] = f2b(v);
        }
    } else if (blk < PB_CODE) {
        int e = (blk - PB_WR) * 256 + tid;
        if (e < N_EDGES)
            codeA[e] = (unsigned char)(bfeat[e * 3] | (bfeat[e * 3 + 1] << 2) | (bfeat[e * 3 + 2] << 4));
    } else {
        if (tid < 128) {
            int t = blk - PB_CODE;
            int l = t >> 6, cd = t & 63, c = tid;
            int f0 = cd & 3, f1 = (cd >> 2) & 3, f2 = cd >> 4;
            const float* W = preW + (size_t)l * 384 * 128 + 256 * 128;
            float acc = preB[l * 128 + c];
            #pragma unroll 4
            for (int k = 0; k < EMB; ++k) {
                float bsk = bemb[(0 * VOCAB + f0) * EMB + k]
                          + bemb[(1 * VOCAB + f1) * EMB + k]
                          + bemb[(2 * VOCAB + f2) * EMB + k];
                acc += bsk * W[k * 128 + c];
            }
            Tb[(size_t)(l * 64 + cd) * 128 + c] = f2b(acc);
        }
    }
}

// ---------------- layer-0 Z12 GEMM: z12 = h @ wb0 (R7-verified v1) ----------------
__global__ __launch_bounds__(256) void gemm_z12(const bf16* __restrict__ A,
                                                const bf16* __restrict__ Bp,
                                                bf16* __restrict__ C) {
    int lane = threadIdx.x & 63;
    int wave = threadIdx.x >> 6;
    int m = lane & 15, quad = lane >> 4;
    int row0 = blockIdx.x * 64 + wave * 16;

    frag_cd acc[16];
    #pragma unroll
    for (int nt = 0; nt < 16; ++nt)
        #pragma unroll
        for (int i = 0; i < 4; ++i) acc[nt][i] = 0.f;

    const frag_ab* Bf = (const frag_ab*)Bp;
    const bf16* arow = A + (size_t)(row0 + m) * 128;
    #pragma unroll
    for (int ks = 0; ks < 4; ++ks) {
        frag_ab a = *(const frag_ab*)(arow + ks * 32 + quad * 8);
        #pragma unroll
        for (int nt = 0; nt < 16; ++nt) {
            frag_ab b = Bf[(ks * 16 + nt) * 64 + lane];
            acc[nt] = __builtin_amdgcn_mfma_f32_16x16x32_bf16(a, b, acc[nt], 0, 0, 0);
        }
    }
    #pragma unroll
    for (int nt = 0; nt < 16; ++nt) {
        int col = nt * 16 + m;
        #pragma unroll
        for (int r = 0; r < 4; ++r) {
            int row = row0 + quad * 4 + r;
            C[(size_t)row * 256 + col] = f2b(acc[nt][r]);
        }
    }
}

// ---------------- fully fused layer (R7-verified v6 config) ----------------
// Block = 32 nodes, 256 threads / 4 waves, LDS 39.4 KB -> 4 blocks/CU.
__global__ __launch_bounds__(256, 4) void fused_layer(bf16* __restrict__ h,
                                                      const bf16* __restrict__ Zcur,
                                                      const int* __restrict__ src,
                                                      const unsigned char* __restrict__ code,
                                                      const float* __restrict__ rand_edge,
                                                      const bf16* __restrict__ Tb,
                                                      const float* __restrict__ Wr,
                                                      const bf16* __restrict__ Bp,
                                                      const float* __restrict__ bias,
                                                      const bf16* __restrict__ Bn,
                                                      bf16* __restrict__ Znext) {
    __shared__ __align__(16) bf16 agg_lds[32 * 520];   // 33,280 B
    __shared__ __align__(16) float relds[4][384];      // 6,144 B

    int tid = threadIdx.x;
    int lane = tid & 63, wave = tid >> 6;
    int ml = lane & 15, quad = lane >> 4;
    int row0 = blockIdx.x * 32;

    const unsigned short* Zu = (const unsigned short*)Zcur;
    const unsigned short* Tu = (const unsigned short*)Tb;
    unsigned short* Ag = (unsigned short*)agg_lds;
    int c = lane * 2;

    // ================= agg phase: per-wave, no barriers (2-slot pipeline) =================
    {
        const int vbase = row0 + wave * 8;

        f32x2 wr2[16];
        #pragma unroll
        for (int k = 0; k < 16; ++k) {
            float2 w2 = *(const float2*)(Wr + k * 128 + c);
            wr2[k].x = w2.x; wr2[k].y = w2.y;
        }

        {
            const float2* rb = (const float2*)(rand_edge + (size_t)vbase * 96);
            float2 a0 = rb[lane], a1 = rb[lane + 64], a2 = rb[lane + 128];
            float2* rl = (float2*)relds[wave];
            rl[lane] = a0; rl[lane + 64] = a1; rl[lane + 128] = a2;
        }
        float2 rh0, rh1, rh2;

        int svs[2][6]; int cds[2][6];
        ushort2 z1u[2][6], tvu[2][6], z2u[2];

        {
            const int2* sp = (const int2*)(src + vbase * 6);
            int2 a = sp[0], b = sp[1], d = sp[2];
            svs[0][0] = a.x; svs[0][1] = a.y; svs[0][2] = b.x;
            svs[0][3] = b.y; svs[0][4] = d.x; svs[0][5] = d.y;
            const unsigned short* cp = (const unsigned short*)(code + vbase * 6);
            unsigned short x = cp[0], y = cp[1], z = cp[2];
            cds[0][0] = x & 255; cds[0][1] = x >> 8; cds[0][2] = y & 255;
            cds[0][3] = y >> 8;  cds[0][4] = z & 255; cds[0][5] = z >> 8;
        }
        z2u[0] = *(const ushort2*)(Zu + (size_t)vbase * 256 + 128 + c);
        #pragma unroll
        for (int j = 0; j < 6; ++j) z1u[0][j] = *(const ushort2*)(Zu + (size_t)svs[0][j] * 256 + c);
        #pragma unroll
        for (int j = 0; j < 6; ++j) tvu[0][j] = *(const ushort2*)(Tu + cds[0][j] * 128 + c);
        {
            const int2* sp = (const int2*)(src + (vbase + 1) * 6);
            int2 a = sp[0], b = sp[1], d = sp[2];
            svs[1][0] = a.x; svs[1][1] = a.y; svs[1][2] = b.x;
            svs[1][3] = b.y; svs[1][4] = d.x; svs[1][5] = d.y;
            const unsigned short* cp = (const unsigned short*)(code + (vbase + 1) * 6);
            unsigned short x = cp[0], y = cp[1], z = cp[2];
            cds[1][0] = x & 255; cds[1][1] = x >> 8; cds[1][2] = y & 255;
            cds[1][3] = y >> 8;  cds[1][4] = z & 255; cds[1][5] = z >> 8;
        }

        #pragma unroll
        for (int i = 0; i < 8; ++i) {
            const int s = i & 1, t = s ^ 1;
            if (i == 2) {
                const float2* rb2 = (const float2*)(rand_edge + (size_t)(vbase + 4) * 96);
                rh0 = rb2[lane]; rh1 = rb2[lane + 64]; rh2 = rb2[lane + 128];
            }
            if (i == 4) {
                float2* rl = (float2*)relds[wave];
                rl[lane] = rh0; rl[lane + 64] = rh1; rl[lane + 128] = rh2;
            }
            if (i < 7) {
                z2u[t] = *(const ushort2*)(Zu + (size_t)(vbase + i + 1) * 256 + 128 + c);
                #pragma unroll
                for (int j = 0; j < 6; ++j) z1u[t][j] = *(const ushort2*)(Zu + (size_t)svs[t][j] * 256 + c);
                #pragma unroll
                for (int j = 0; j < 6; ++j) tvu[t][j] = *(const ushort2*)(Tu + cds[t][j] * 128 + c);
            }
            if (i < 6) {
                const int2* sp = (const int2*)(src + (vbase + i + 2) * 6);
                int2 a = sp[0], b = sp[1], d = sp[2];
                svs[s][0] = a.x; svs[s][1] = a.y; svs[s][2] = b.x;
                svs[s][3] = b.y; svs[s][4] = d.x; svs[s][5] = d.y;
                const unsigned short* cp = (const unsigned short*)(code + (vbase + i + 2) * 6);
                unsigned short x = cp[0], y = cp[1], z = cp[2];
                cds[s][0] = x & 255; cds[s][1] = x >> 8; cds[s][2] = y & 255;
                cds[s][3] = y >> 8;  cds[s][4] = z & 255; cds[s][5] = z >> 8;
            }

            float z2a = us2f(z2u[s].x), z2b = us2f(z2u[s].y);
            f32x2 s2  = {0.f, 0.f}, ss2 = {0.f, 0.f};
            f32x2 mx2 = {-1e30f, -1e30f}, mn2 = {1e30f, 1e30f};
            #pragma unroll
            for (int j = 0; j < 6; ++j) {
                const float4* rp = (const float4*)&relds[wave][(i & 3) * 96 + j * 16];
                float4 r0 = rp[0], r1 = rp[1], r2 = rp[2], r3 = rp[3];
                f32x2 v2;
                v2.x = us2f(z1u[s][j].x) + z2a + us2f(tvu[s][j].x);
                v2.y = us2f(z1u[s][j].y) + z2b + us2f(tvu[s][j].y);
                float rk[16] = {r0.x, r0.y, r0.z, r0.w, r1.x, r1.y, r1.z, r1.w,
                                r2.x, r2.y, r2.z, r2.w, r3.x, r3.y, r3.z, r3.w};
                #pragma unroll
                for (int k = 0; k < 16; ++k) v2 += rk[k] * wr2[k];
                v2 = __builtin_elementwise_max(v2, (f32x2){0.f, 0.f});
                s2 += v2;
                ss2 += v2 * v2;
                mx2 = __builtin_elementwise_max(mx2, v2);
                mn2 = __builtin_elementwise_min(mn2, v2);
            }
            f32x2 mean2 = s2 * (1.f / 6.f);
            f32x2 msq2  = ss2 * (1.f / 6.f);
            f32x2 var2  = __builtin_elementwise_max(msq2 - mean2 * mean2, (f32x2){0.f, 0.f});
            float sda = sqrtf(var2.x + 1e-5f), sdb = sqrtf(var2.y + 1e-5f);
            int lrow = wave * 8 + i;
            size_t base = (size_t)lrow * 520 + c;
            *(ushort2*)(Ag + base)       = make_ushort2(f2us(mean2.x), f2us(mean2.y));
            *(ushort2*)(Ag + base + 128) = make_ushort2(f2us(mx2.x),   f2us(mx2.y));
            *(ushort2*)(Ag + base + 256) = make_ushort2(f2us(mn2.x),   f2us(mn2.y));
            *(ushort2*)(Ag + base + 384) = make_ushort2(f2us(sda),     f2us(sdb));
        }
    }
    __syncthreads();   // (1) agg tile complete

    // ================= GEMM phase =================
    int ng = wave;

    frag_cd acc[2][2];
    #pragma unroll
    for (int m2 = 0; m2 < 2; ++m2)
        #pragma unroll
        for (int nt = 0; nt < 2; ++nt)
            #pragma unroll
            for (int i = 0; i < 4; ++i) acc[m2][nt][i] = 0.f;

    const frag_ab* Bf = (const frag_ab*)Bp;
    #pragma unroll
    for (int ks = 0; ks < 4; ++ks) {
        frag_ab b0 = Bf[(ks * 8 + ng * 2 + 0) * 64 + lane];
        frag_ab b1 = Bf[(ks * 8 + ng * 2 + 1) * 64 + lane];
        #pragma unroll
        for (int m2 = 0; m2 < 2; ++m2) {
            frag_ab a = *(const frag_ab*)(h + (size_t)(row0 + m2 * 16 + ml) * 128 + ks * 32 + quad * 8);
            acc[m2][0] = __builtin_amdgcn_mfma_f32_16x16x32_bf16(a, b0, acc[m2][0], 0, 0, 0);
            acc[m2][1] = __builtin_amdgcn_mfma_f32_16x16x32_bf16(a, b1, acc[m2][1], 0, 0, 0);
        }
    }
    #pragma unroll
    for (int ks = 0; ks < 16; ++ks) {
        frag_ab b0 = Bf[((4 + ks) * 8 + ng * 2 + 0) * 64 + lane];
        frag_ab b1 = Bf[((4 + ks) * 8 + ng * 2 + 1) * 64 + lane];
        #pragma unroll
        for (int m2 = 0; m2 < 2; ++m2) {
            frag_ab a = *(const frag_ab*)(agg_lds + (size_t)(m2 * 16 + ml) * 520 + ks * 32 + quad * 8);
            acc[m2][0] = __builtin_amdgcn_mfma_f32_16x16x32_bf16(a, b0, acc[m2][0], 0, 0, 0);
            acc[m2][1] = __builtin_amdgcn_mfma_f32_16x16x32_bf16(a, b1, acc[m2][1], 0, 0, 0);
        }
    }

    __syncthreads();   // (2)

    float* pgemm = (float*)agg_lds;   // [32][132]
    #pragma unroll
    for (int nt = 0; nt < 2; ++nt) {
        int col = (ng * 2 + nt) * 16 + ml;
        float bs_ = bias[col];
        #pragma unroll
        for (int m2 = 0; m2 < 2; ++m2) {
            #pragma unroll
            for (int r2 = 0; r2 < 4; ++r2) {
                int lr = m2 * 16 + quad * 4 + r2;
                pgemm[lr * 132 + col] = acc[m2][nt][r2] + bs_;
            }
        }
    }
    __syncthreads();   // (3)

    bf16* newh = agg_lds + 8448;   // [32][136]
    {
        int row = tid >> 3, cg = tid & 7;
        const float4* pg = (const float4*)(pgemm + row * 132 + cg * 16);
        float4 p0 = pg[0], p1 = pg[1], p2 = pg[2], p3 = pg[3];
        unsigned short* hrow = (unsigned short*)(h + (size_t)(row0 + row) * 128 + cg * 16);
        frag_ab h0 = *(const frag_ab*)hrow;
        frag_ab h1 = *(const frag_ab*)(hrow + 8);
        float nv[16] = {p0.x, p0.y, p0.z, p0.w, p1.x, p1.y, p1.z, p1.w,
                        p2.x, p2.y, p2.z, p2.w, p3.x, p3.y, p3.z, p3.w};
        #pragma unroll
        for (int j = 0; j < 8; ++j) nv[j]     += us2f((unsigned short)h0[j]);
        #pragma unroll
        for (int j = 0; j < 8; ++j) nv[8 + j] += us2f((unsigned short)h1[j]);
        frag_ab o0, o1;
        #pragma unroll
        for (int j = 0; j < 8; ++j) o0[j] = (short)f2us(nv[j]);
        #pragma unroll
        for (int j = 0; j < 8; ++j) o1[j] = (short)f2us(nv[8 + j]);
        *(frag_ab*)hrow = o0;
        *(frag_ab*)(hrow + 8) = o1;
        *(frag_ab*)&newh[row * 136 + cg * 16] = o0;
        *(frag_ab*)&newh[row * 136 + cg * 16 + 8] = o1;
    }

    if (Bn) {
        __syncthreads();   // (4)
        const frag_ab* Bf2 = (const frag_ab*)Bn;
        frag_cd a2[2][4];
        #pragma unroll
        for (int m2 = 0; m2 < 2; ++m2)
            #pragma unroll
            for (int nt = 0; nt < 4; ++nt)
                #pragma unroll
                for (int i = 0; i < 4; ++i) a2[m2][nt][i] = 0.f;
        #pragma unroll
        for (int ks = 0; ks < 4; ++ks) {
            frag_ab bb[4];
            #pragma unroll
            for (int nt = 0; nt < 4; ++nt)
                bb[nt] = Bf2[(ks * 16 + ng * 4 + nt) * 64 + lane];
            #pragma unroll
            for (int m2 = 0; m2 < 2; ++m2) {
                frag_ab a = *(const frag_ab*)&newh[(m2 * 16 + ml) * 136 + ks * 32 + quad * 8];
                #pragma unroll
                for (int nt = 0; nt < 4; ++nt)
                    a2[m2][nt] = __builtin_amdgcn_mfma_f32_16x16x32_bf16(a, bb[nt], a2[m2][nt], 0, 0, 0);
            }
        }
        bf16* ztile = agg_lds;   // [32][264]
        #pragma unroll
        for (int m2 = 0; m2 < 2; ++m2) {
            #pragma unroll
            for (int nt = 0; nt < 4; ++nt) {
                int col = (ng * 4 + nt) * 16 + ml;
                #pragma unroll
                for (int r2 = 0; r2 < 4; ++r2) {
                    int lr = m2 * 16 + quad * 4 + r2;
                    ztile[lr * 264 + col] = f2b(a2[m2][nt][r2]);
                }
            }
        }
        __syncthreads();   // (5)
        int row = tid >> 3, cg = tid & 7;
        unsigned short* zr = (unsigned short*)(Znext + (size_t)(row0 + row) * 256 + cg * 32);
        const unsigned short* zs = (const unsigned short*)ztile + row * 264 + cg * 32;
        #pragma unroll
        for (int k2 = 0; k2 < 4; ++k2)
            *(frag_ab*)(zr + k2 * 8) = *(const frag_ab*)(zs + k2 * 8);
    }
}

// ---------------- readout (R7-verified v1) ----------------
__global__ __launch_bounds__(128) void readout(const bf16* __restrict__ h, const float* __restrict__ W1,
                                               const float* __restrict__ b1, const float* __restrict__ W2,
                                               const float* __restrict__ b2, float* __restrict__ out) {
    __shared__ float r[384];
    __shared__ float y1[128];
    int g = blockIdx.x, c = threadIdx.x;
    float s = 0.f, mx = -1e30f;
    for (int v = 0; v < 128; ++v) {
        float hv = b2f(h[((size_t)g * 128 + v) * HID + c]);
        s += hv; mx = fmaxf(mx, hv);
    }
    r[c] = s * (1.f / 128.f);
    r[128 + c] = s;
    r[256 + c] = mx;
    __syncthreads();
    float a1 = b1[c];
    for (int k = 0; k < 384; ++k) a1 += r[k] * W1[k * 128 + c];
    y1[c] = fmaxf(a1, 0.f);
    __syncthreads();
    #pragma unroll
    for (int o = 0; o < 2; ++o) {
        int t = c + o * 128;
        float a2 = b2[t];
        for (int k = 0; k < 128; ++k) a2 += y1[k] * W2[k * 256 + t];
        out[(size_t)g * 256 + t] = a2;
    }
}

// ---------------- launch ----------------
extern "C" void kernel_launch(void* const* d_in, const int* in_sizes, int n_in,
                              void* d_out, int out_size, void* d_ws, size_t ws_size,
                              hipStream_t stream) {
    const int*   atom_feats = (const int*)d_in[0];
    const int*   bond_feats = (const int*)d_in[1];
    const int*   src        = (const int*)d_in[2];
    const float* rand_x     = (const float*)d_in[6];
    const float* rand_edge  = (const float*)d_in[7];
    const float* atom_emb   = (const float*)d_in[8];
    const float* bond_emb   = (const float*)d_in[9];
    const float* pre_W      = (const float*)d_in[10];
    const float* pre_b      = (const float*)d_in[11];
    const float* post_W     = (const float*)d_in[12];
    const float* post_b     = (const float*)d_in[13];
    const float* ro_W1      = (const float*)d_in[14];
    const float* ro_b1      = (const float*)d_in[15];
    const float* ro_W2      = (const float*)d_in[16];
    const float* ro_b2      = (const float*)d_in[17];

    char* p = (char*)d_ws;
    auto alloc = [&](size_t bytes) {
        char* r = p;
        p += (bytes + 255) & ~(size_t)255;
        return r;
    };
    bf16*  h    = (bf16*) alloc((size_t)N_NODES * HID * 2);      // 8 MB (bf16 state)
    bf16*  z12a = (bf16*) alloc((size_t)N_NODES * 256 * 2);      // 16 MB (ping)
    bf16*  z12b = (bf16*) alloc((size_t)N_NODES * 256 * 2);      // 16 MB (pong)
    bf16*  wb   = (bf16*) alloc((size_t)DEPTH * 32768 * 2);
    bf16*  wc   = (bf16*) alloc((size_t)DEPTH * 81920 * 2);
    bf16*  wrB  = (bf16*) alloc((size_t)DEPTH * 4096 * 2);       // 40 KB (legacy pack, unused)
    bf16*  Tb   = (bf16*) alloc((size_t)DEPTH * 64 * 128 * 2);   // 80 KB
    unsigned char* code = (unsigned char*)alloc(N_EDGES);        // 192 KB

    // unified prep (encode + all packs + bond table)
    prep_k<<<PB_T, 256, 0, stream>>>(atom_feats, rand_x, atom_emb, h,
                                     pre_W, pre_b, post_W,
                                     bond_feats, bond_emb,
                                     wb, wc, wrB, code, Tb);

    // layer-0 Z12
    gemm_z12<<<N_NODES / 64, 256, 0, stream>>>(h, wb, z12a);

    bf16* zc = z12a;
    bf16* zn = z12b;
    for (int l = 0; l < DEPTH; ++l) {
        const bf16* wbn = (l + 1 < DEPTH) ? (wb + (size_t)(l + 1) * 32768) : nullptr;
        fused_layer<<<N_NODES / 32, 256, 0, stream>>>(
            h, zc, src, code, rand_edge,
            Tb + (size_t)l * 8192,
            pre_W + (size_t)l * 384 * 128 + 368 * 128,   // Wr: rand-edge rows of pretrans W
            wc + (size_t)l * 81920,
            post_b + l * HID,
            wbn, zn);
        bf16* t = zc; zc = zn; zn = t;
    }

    readout<<<N_GRAPHS, 128, 0, stream>>>(h, ro_W1, ro_b1, ro_W2, ro_b2, (float*)d_out);
}